// Round 5
// baseline (522.796 us; speedup 1.0000x reference)
//
#include <hip/hip_runtime.h>

// SSIM loss, separable 11-tap Gaussian (g = row sums of the 2D window).
// R5: back to R1's wide-parallel 3-phase structure (the only one that kept
// VALU busy), with the LDS pipe cost cut ~4x by bf16 packing + b128 ops:
//   stage: (x,y) packed as 2xbf16 in one uint  [42x48]
//   horiz: 16-uint b128 reads -> 4 outputs/thread; h packed (hx,hy),(hxx,hyy)
//          as uints + hxy as ushort  -> 2.5 words/px instead of 5
//   vert:  11 rows x b128 packed reads, 4 cols/thread
// Numerics: bf16 (RNE) inputs + f32 taps/accum — validated by R4 (0.0078).
// LDS 21.6KB, __launch_bounds__(256,4): 4 blocks/CU, VGPR<=128.

#define WSZ 11

__device__ __forceinline__ unsigned bfr(float f) {   // f32 -> bf16 bits (RNE)
    unsigned u = __float_as_uint(f);
    u += 0x7fffu + ((u >> 16) & 1u);
    return u >> 16;
}
__device__ __forceinline__ float bflo(unsigned u) {  // low 16 bits -> f32
    return __uint_as_float(u << 16);
}
__device__ __forceinline__ float bfhi(unsigned u) {  // high 16 bits -> f32
    return __uint_as_float(u & 0xffff0000u);
}

__global__ void ssim_init(float* ws) {
    if (threadIdx.x == 0) { ws[0] = 0.0f; ((unsigned*)ws)[1] = 0u; }
}

__global__ __launch_bounds__(256, 4) void ssim_main(
    const float* __restrict__ xg, const float* __restrict__ yg,
    const float* __restrict__ w2d, float* __restrict__ ws,
    float* __restrict__ out, int nblocks, float invN)
{
    __shared__ __align__(16) unsigned sxy[42 * 48];       // 8.1 KB
    __shared__ __align__(16) unsigned hxhy[42 * 32];      // 5.4 KB
    __shared__ __align__(16) unsigned hxxyy[42 * 32];     // 5.4 KB
    __shared__ __align__(16) unsigned short hxys[42 * 32];// 2.7 KB
    __shared__ float gs[WSZ];
    __shared__ float wred[4];

    const int tid = threadIdx.x;

    // 1D kernel = row sums of the 2D window (window = outer(g,g), sum 1).
    if (tid < WSZ) {
        float s = 0.0f;
        #pragma unroll
        for (int j = 0; j < WSZ; ++j) s += w2d[tid * WSZ + j];
        gs[tid] = s;
    }

    const int x0 = blockIdx.x * 32 - 5;
    const int y0 = blockIdx.y * 32 - 5;
    const size_t zoff = (size_t)blockIdx.z * (512 * 512);
    const float* __restrict__ xp = xg + zoff;
    const float* __restrict__ yp = yg + zoff;

    // Phase A: stage 42x48 tile, zero-padded, packed bf16(x)|bf16(y)<<16.
    for (int it = tid; it < 42 * 48; it += 256) {
        const int r = it / 48, c = it - r * 48;
        const int gr = y0 + r, gc = x0 + c;
        float xv = 0.0f, yv = 0.0f;
        if ((unsigned)gr < 512u && (unsigned)gc < 512u) {
            const int o = gr * 512 + gc;
            xv = xp[o]; yv = yp[o];
        }
        sxy[it] = bfr(xv) | (bfr(yv) << 16);
    }
    __syncthreads();

    float g[WSZ];
    #pragma unroll
    for (int k = 0; k < WSZ; ++k) g[k] = gs[k];

    // Phase B: horizontal pass. Item = (row, col-quad): 4 outputs from
    // 4 aligned uint4 LDS reads (16 packed px, taps use [0..13]).
    for (int it = tid; it < 42 * 8; it += 256) {
        const int r = it >> 3, q = it & 7;
        const unsigned* p = &sxy[r * 48 + 4 * q];
        unsigned uu[16];
        *(uint4*)&uu[0]  = *(const uint4*)(p);
        *(uint4*)&uu[4]  = *(const uint4*)(p + 4);
        *(uint4*)&uu[8]  = *(const uint4*)(p + 8);
        *(uint4*)&uu[12] = *(const uint4*)(p + 12);
        float xa[14], ya[14];
        #pragma unroll
        for (int i = 0; i < 14; ++i) { xa[i] = bflo(uu[i]); ya[i] = bfhi(uu[i]); }

        float ax[4], ay[4], axx[4], ayy[4], axy[4];
        #pragma unroll
        for (int j = 0; j < 4; ++j)
            ax[j] = ay[j] = axx[j] = ayy[j] = axy[j] = 0.0f;
        #pragma unroll
        for (int k = 0; k < WSZ; ++k) {
            const float gv = g[k];
            #pragma unroll
            for (int j = 0; j < 4; ++j) {
                const float xv = xa[j + k], yv = ya[j + k];
                ax[j]  = fmaf(gv, xv, ax[j]);
                ay[j]  = fmaf(gv, yv, ay[j]);
                axx[j] = fmaf(gv, xv * xv, axx[j]);
                ayy[j] = fmaf(gv, yv * yv, ayy[j]);
                axy[j] = fmaf(gv, xv * yv, axy[j]);
            }
        }
        const int o = r * 32 + 4 * q;
        uint4 w1, w2;
        w1.x = bfr(ax[0]) | (bfr(ay[0]) << 16);
        w1.y = bfr(ax[1]) | (bfr(ay[1]) << 16);
        w1.z = bfr(ax[2]) | (bfr(ay[2]) << 16);
        w1.w = bfr(ax[3]) | (bfr(ay[3]) << 16);
        w2.x = bfr(axx[0]) | (bfr(ayy[0]) << 16);
        w2.y = bfr(axx[1]) | (bfr(ayy[1]) << 16);
        w2.z = bfr(axx[2]) | (bfr(ayy[2]) << 16);
        w2.w = bfr(axx[3]) | (bfr(ayy[3]) << 16);
        *(uint4*)&hxhy[o]  = w1;
        *(uint4*)&hxxyy[o] = w2;
        *(ushort4*)&hxys[o] = make_ushort4(
            (unsigned short)bfr(axy[0]), (unsigned short)bfr(axy[1]),
            (unsigned short)bfr(axy[2]), (unsigned short)bfr(axy[3]));
    }
    __syncthreads();

    // Phase C: vertical pass + SSIM. Thread = (row, col-quad), 4 outputs.
    const int q = tid & 7, r = tid >> 3;     // r in 0..31
    const int c0 = 4 * q;
    float m[5][4];
    #pragma unroll
    for (int t = 0; t < 5; ++t)
        #pragma unroll
        for (int j = 0; j < 4; ++j) m[t][j] = 0.0f;

    #pragma unroll
    for (int k = 0; k < WSZ; ++k) {
        const int o = (r + k) * 32 + c0;
        const uint4 a = *(const uint4*)&hxhy[o];
        const uint4 b = *(const uint4*)&hxxyy[o];
        const ushort4 s4 = *(const ushort4*)&hxys[o];
        const unsigned aa[4] = {a.x, a.y, a.z, a.w};
        const unsigned bb[4] = {b.x, b.y, b.z, b.w};
        const unsigned cc[4] = {s4.x, s4.y, s4.z, s4.w};
        const float gv = g[k];
        #pragma unroll
        for (int j = 0; j < 4; ++j) {
            m[0][j] = fmaf(gv, bflo(aa[j]), m[0][j]);
            m[1][j] = fmaf(gv, bfhi(aa[j]), m[1][j]);
            m[2][j] = fmaf(gv, bflo(bb[j]), m[2][j]);
            m[3][j] = fmaf(gv, bfhi(bb[j]), m[3][j]);
            m[4][j] = fmaf(gv, __uint_as_float(cc[j] << 16), m[4][j]);
        }
    }

    float lsum = 0.0f;
    const float C1 = 1e-4f, C2 = 9e-4f;
    #pragma unroll
    for (int j = 0; j < 4; ++j) {
        const float mx = m[0][j], my = m[1][j];
        const float exx = m[2][j], eyy = m[3][j], exy = m[4][j];
        const float mx2 = mx * mx, my2 = my * my, mxy = mx * my;
        const float vx = exx - mx2, vy = eyy - my2, vxy = exy - mxy;
        const float num = (2.0f * mxy + C1) * (2.0f * vxy + C2);
        const float den = (mx2 + my2 + C1) * (vx + vy + C2) + 1e-12f;
        // den >= C1*C2 > 0; v_rcp_f32 rel err ~1e-5 << 2e-2 threshold.
        lsum = fmaf(num, __builtin_amdgcn_rcpf(den), lsum);
    }

    // Wave reduce -> cross-wave -> one atomic; last block finalizes.
    #pragma unroll
    for (int off = 32; off > 0; off >>= 1)
        lsum += __shfl_down(lsum, off, 64);
    if ((tid & 63) == 0) wred[tid >> 6] = lsum;
    __syncthreads();
    if (tid == 0) {
        atomicAdd(&ws[0], wred[0] + wred[1] + wred[2] + wred[3]);
        __threadfence();
        const unsigned old = atomicAdd((unsigned*)ws + 1, 1u);
        if (old == (unsigned)(nblocks - 1)) {
            __threadfence();
            const float total = atomicAdd(&ws[0], 0.0f);
            out[0] = 1.0f - total * invN;
        }
    }
}

extern "C" void kernel_launch(void* const* d_in, const int* in_sizes, int n_in,
                              void* d_out, int out_size, void* d_ws, size_t ws_size,
                              hipStream_t stream) {
    const float* x   = (const float*)d_in[0];
    const float* y   = (const float*)d_in[1];
    const float* w2d = (const float*)d_in[2];  // (3,1,11,11); channels identical
    float* out = (float*)d_out;
    float* ws  = (float*)d_ws;

    const int H = 512, W = 512;
    const int total = in_sizes[0];              // 16*3*512*512
    const int Z = total / (H * W);              // 48

    ssim_init<<<1, 64, 0, stream>>>(ws);

    dim3 grid(W / 32, H / 32, Z);               // 16 x 16 x 48 = 12288 blocks
    const int nblocks = (W / 32) * (H / 32) * Z;
    const float invN = 1.0f / (float)total;
    ssim_main<<<grid, 256, 0, stream>>>(x, y, w2d, ws, out, nblocks, invN);
}

// Round 6
// 228.407 us; speedup vs baseline: 2.2889x; 2.2889x over previous
//
#include <hip/hip_runtime.h>

// SSIM loss, separable 11-tap Gaussian (g = row sums of the 2D window).
// R6: remove the same-address atomic serialization. Cross-round evidence:
// VALU busy-time is ~100us in every round while duration tracks the count of
// same-cacheline atomics (12288 -> 182us, 24576 -> 338/413/440us); R4's
// L3-resident replays (0.8MB HBM) still took 428us -> serialization, not
// memory. Fix: per-block partial -> plain store to ws[blockId] (disjoint),
// tiny reduce kernel sums 12288 floats and writes the scalar.
// Compute body unchanged from R5 (controlled experiment).

#define WSZ 11

__device__ __forceinline__ unsigned bfr(float f) {   // f32 -> bf16 bits (RNE)
    unsigned u = __float_as_uint(f);
    u += 0x7fffu + ((u >> 16) & 1u);
    return u >> 16;
}
__device__ __forceinline__ float bflo(unsigned u) {  // low 16 bits -> f32
    return __uint_as_float(u << 16);
}
__device__ __forceinline__ float bfhi(unsigned u) {  // high 16 bits -> f32
    return __uint_as_float(u & 0xffff0000u);
}

__global__ __launch_bounds__(256, 4) void ssim_main(
    const float* __restrict__ xg, const float* __restrict__ yg,
    const float* __restrict__ w2d, float* __restrict__ part)
{
    __shared__ __align__(16) unsigned sxy[42 * 48];       // 8.1 KB
    __shared__ __align__(16) unsigned hxhy[42 * 32];      // 5.4 KB
    __shared__ __align__(16) unsigned hxxyy[42 * 32];     // 5.4 KB
    __shared__ __align__(16) unsigned short hxys[42 * 32];// 2.7 KB
    __shared__ float gs[WSZ];
    __shared__ float wred[4];

    const int tid = threadIdx.x;

    // 1D kernel = row sums of the 2D window (window = outer(g,g), sum 1).
    if (tid < WSZ) {
        float s = 0.0f;
        #pragma unroll
        for (int j = 0; j < WSZ; ++j) s += w2d[tid * WSZ + j];
        gs[tid] = s;
    }

    const int x0 = blockIdx.x * 32 - 5;
    const int y0 = blockIdx.y * 32 - 5;
    const size_t zoff = (size_t)blockIdx.z * (512 * 512);
    const float* __restrict__ xp = xg + zoff;
    const float* __restrict__ yp = yg + zoff;

    // Phase A: stage 42x48 tile, zero-padded, packed bf16(x)|bf16(y)<<16.
    for (int it = tid; it < 42 * 48; it += 256) {
        const int r = it / 48, c = it - r * 48;
        const int gr = y0 + r, gc = x0 + c;
        float xv = 0.0f, yv = 0.0f;
        if ((unsigned)gr < 512u && (unsigned)gc < 512u) {
            const int o = gr * 512 + gc;
            xv = xp[o]; yv = yp[o];
        }
        sxy[it] = bfr(xv) | (bfr(yv) << 16);
    }
    __syncthreads();

    float g[WSZ];
    #pragma unroll
    for (int k = 0; k < WSZ; ++k) g[k] = gs[k];

    // Phase B: horizontal pass. Item = (row, col-quad): 4 outputs from
    // 4 aligned uint4 LDS reads (16 packed px, taps use [0..13]).
    for (int it = tid; it < 42 * 8; it += 256) {
        const int r = it >> 3, q = it & 7;
        const unsigned* p = &sxy[r * 48 + 4 * q];
        unsigned uu[16];
        *(uint4*)&uu[0]  = *(const uint4*)(p);
        *(uint4*)&uu[4]  = *(const uint4*)(p + 4);
        *(uint4*)&uu[8]  = *(const uint4*)(p + 8);
        *(uint4*)&uu[12] = *(const uint4*)(p + 12);
        float xa[14], ya[14];
        #pragma unroll
        for (int i = 0; i < 14; ++i) { xa[i] = bflo(uu[i]); ya[i] = bfhi(uu[i]); }

        float ax[4], ay[4], axx[4], ayy[4], axy[4];
        #pragma unroll
        for (int j = 0; j < 4; ++j)
            ax[j] = ay[j] = axx[j] = ayy[j] = axy[j] = 0.0f;
        #pragma unroll
        for (int k = 0; k < WSZ; ++k) {
            const float gv = g[k];
            #pragma unroll
            for (int j = 0; j < 4; ++j) {
                const float xv = xa[j + k], yv = ya[j + k];
                ax[j]  = fmaf(gv, xv, ax[j]);
                ay[j]  = fmaf(gv, yv, ay[j]);
                axx[j] = fmaf(gv, xv * xv, axx[j]);
                ayy[j] = fmaf(gv, yv * yv, ayy[j]);
                axy[j] = fmaf(gv, xv * yv, axy[j]);
            }
        }
        const int o = r * 32 + 4 * q;
        uint4 w1, w2;
        w1.x = bfr(ax[0]) | (bfr(ay[0]) << 16);
        w1.y = bfr(ax[1]) | (bfr(ay[1]) << 16);
        w1.z = bfr(ax[2]) | (bfr(ay[2]) << 16);
        w1.w = bfr(ax[3]) | (bfr(ay[3]) << 16);
        w2.x = bfr(axx[0]) | (bfr(ayy[0]) << 16);
        w2.y = bfr(axx[1]) | (bfr(ayy[1]) << 16);
        w2.z = bfr(axx[2]) | (bfr(ayy[2]) << 16);
        w2.w = bfr(axx[3]) | (bfr(ayy[3]) << 16);
        *(uint4*)&hxhy[o]  = w1;
        *(uint4*)&hxxyy[o] = w2;
        *(ushort4*)&hxys[o] = make_ushort4(
            (unsigned short)bfr(axy[0]), (unsigned short)bfr(axy[1]),
            (unsigned short)bfr(axy[2]), (unsigned short)bfr(axy[3]));
    }
    __syncthreads();

    // Phase C: vertical pass + SSIM. Thread = (row, col-quad), 4 outputs.
    const int q = tid & 7, r = tid >> 3;     // r in 0..31
    const int c0 = 4 * q;
    float m[5][4];
    #pragma unroll
    for (int t = 0; t < 5; ++t)
        #pragma unroll
        for (int j = 0; j < 4; ++j) m[t][j] = 0.0f;

    #pragma unroll
    for (int k = 0; k < WSZ; ++k) {
        const int o = (r + k) * 32 + c0;
        const uint4 a = *(const uint4*)&hxhy[o];
        const uint4 b = *(const uint4*)&hxxyy[o];
        const ushort4 s4 = *(const ushort4*)&hxys[o];
        const unsigned aa[4] = {a.x, a.y, a.z, a.w};
        const unsigned bb[4] = {b.x, b.y, b.z, b.w};
        const unsigned cc[4] = {s4.x, s4.y, s4.z, s4.w};
        const float gv = g[k];
        #pragma unroll
        for (int j = 0; j < 4; ++j) {
            m[0][j] = fmaf(gv, bflo(aa[j]), m[0][j]);
            m[1][j] = fmaf(gv, bfhi(aa[j]), m[1][j]);
            m[2][j] = fmaf(gv, bflo(bb[j]), m[2][j]);
            m[3][j] = fmaf(gv, bfhi(bb[j]), m[3][j]);
            m[4][j] = fmaf(gv, __uint_as_float(cc[j] << 16), m[4][j]);
        }
    }

    float lsum = 0.0f;
    const float C1 = 1e-4f, C2 = 9e-4f;
    #pragma unroll
    for (int j = 0; j < 4; ++j) {
        const float mx = m[0][j], my = m[1][j];
        const float exx = m[2][j], eyy = m[3][j], exy = m[4][j];
        const float mx2 = mx * mx, my2 = my * my, mxy = mx * my;
        const float vx = exx - mx2, vy = eyy - my2, vxy = exy - mxy;
        const float num = (2.0f * mxy + C1) * (2.0f * vxy + C2);
        const float den = (mx2 + my2 + C1) * (vx + vy + C2) + 1e-12f;
        // den >= C1*C2 > 0; v_rcp_f32 rel err ~1e-5 << 2e-2 threshold.
        lsum = fmaf(num, __builtin_amdgcn_rcpf(den), lsum);
    }

    // Wave reduce -> cross-wave via LDS -> ONE PLAIN STORE per block.
    #pragma unroll
    for (int off = 32; off > 0; off >>= 1)
        lsum += __shfl_down(lsum, off, 64);
    if ((tid & 63) == 0) wred[tid >> 6] = lsum;
    __syncthreads();
    if (tid == 0) {
        const int bid = (blockIdx.z * gridDim.y + blockIdx.y) * gridDim.x
                        + blockIdx.x;
        part[bid] = wred[0] + wred[1] + wred[2] + wred[3];
    }
}

__global__ __launch_bounds__(256) void ssim_reduce(
    const float* __restrict__ part, float* __restrict__ out,
    int n, float invN)
{
    __shared__ float wred[4];
    float s = 0.0f;
    for (int i = threadIdx.x; i < n; i += 256) s += part[i];
    #pragma unroll
    for (int off = 32; off > 0; off >>= 1)
        s += __shfl_down(s, off, 64);
    if ((threadIdx.x & 63) == 0) wred[threadIdx.x >> 6] = s;
    __syncthreads();
    if (threadIdx.x == 0)
        out[0] = 1.0f - (wred[0] + wred[1] + wred[2] + wred[3]) * invN;
}

extern "C" void kernel_launch(void* const* d_in, const int* in_sizes, int n_in,
                              void* d_out, int out_size, void* d_ws, size_t ws_size,
                              hipStream_t stream) {
    const float* x   = (const float*)d_in[0];
    const float* y   = (const float*)d_in[1];
    const float* w2d = (const float*)d_in[2];  // (3,1,11,11); channels identical
    float* out  = (float*)d_out;
    float* part = (float*)d_ws;                // 12288 floats = 48 KB

    const int H = 512, W = 512;
    const int total = in_sizes[0];              // 16*3*512*512
    const int Z = total / (H * W);              // 48

    dim3 grid(W / 32, H / 32, Z);               // 16 x 16 x 48 = 12288 blocks
    const int nblocks = (W / 32) * (H / 32) * Z;
    ssim_main<<<grid, 256, 0, stream>>>(x, y, w2d, part);

    const float invN = 1.0f / (float)total;
    ssim_reduce<<<1, 256, 0, stream>>>(part, out, nblocks, invN);
}

// Round 8
// 174.564 us; speedup vs baseline: 2.9949x; 1.3084x over previous
//
#include <hip/hip_runtime.h>

// SSIM loss, separable 11-tap Gaussian. R7b: VALU-bound (R6: VALUBusy 78%,
// 10.5K wave-instrs/block vs ~27us of useful FMA). Fix: f16 packed math.
//  - v_dot2_f32_f16: 2 taps/instr, f32 accum, consumes packed LDS directly
//    (no unpack trains). Even/odd output phases via two tap vectors Ge/Go.
//  - Horizontal: pixels pair-packed along cols; squares/products via
//    v_pk_mul_f16 (1 instr per pair per quantity).
//  - Vertical: h stored row-pair-packed (v_cvt_pkrtz_f16_f32), dot2 again.
//  - Phase B: 168 items single pass; Phase C: exactly 256 items, full pass.
// Reduction: R6's proven per-block store + tiny reduce kernel (no atomics).
// (R7 fix: h2u overload for __builtin_amdgcn_cvt_pkrtz's __fp16x2 type.)

typedef _Float16 h2 __attribute__((ext_vector_type(2)));
typedef __fp16 fp16x2 __attribute__((ext_vector_type(2)));

__device__ __forceinline__ unsigned h2u(h2 v) { return __builtin_bit_cast(unsigned, v); }
__device__ __forceinline__ unsigned h2u(fp16x2 v) { return __builtin_bit_cast(unsigned, v); }
__device__ __forceinline__ h2 u2h(unsigned u) { return __builtin_bit_cast(h2, u); }

__device__ __forceinline__ float fdot2_(h2 a, h2 b, float c) {
#if defined(__has_builtin) && __has_builtin(__builtin_amdgcn_fdot2)
    return __builtin_amdgcn_fdot2(a, b, c, false);
#else
    return fmaf((float)a[1], (float)b[1], fmaf((float)a[0], (float)b[0], c));
#endif
}

#define SXW 26   // sxy2 row stride (uint2 units); 24 used + pad
#define HPW 36   // hp row stride (words); 32 used + pad

__global__ __launch_bounds__(256, 4) void ssim_main(
    const float* __restrict__ xg, const float* __restrict__ yg,
    const float* __restrict__ w2d, float* __restrict__ part)
{
    __shared__ __align__(16) uint2 sxy2[42 * SXW];      // 8.7 KB  (x|y pairs)
    __shared__ __align__(16) unsigned hp[5 * 21 * HPW]; // 15.1 KB (row-pair h)
    __shared__ float gs[11];
    __shared__ float wred[4];

    const int tid = threadIdx.x;

    // 1D kernel = row sums of the 2D window (window = outer(g,g), sum 1).
    if (tid < 11) {
        float s = 0.0f;
        #pragma unroll
        for (int j = 0; j < 11; ++j) s += w2d[tid * 11 + j];
        gs[tid] = s;
    }

    const int x0 = blockIdx.x * 32 - 5;
    const int y0 = blockIdx.y * 32 - 5;
    const size_t zoff = (size_t)blockIdx.z * (512 * 512);
    const float* __restrict__ xp = xg + zoff;
    const float* __restrict__ yp = yg + zoff;

    // Phase A: stage 42 rows x 24 col-pairs, zero-padded, f16x2-packed.
    for (int it = tid; it < 42 * 24; it += 256) {
        const int r = it / 24, t = it - r * 24;
        const int gr = y0 + r, gc = x0 + 2 * t;
        const bool rok = (unsigned)gr < 512u;
        const int o = gr * 512 + gc;
        float xv0 = 0.f, xv1 = 0.f, yv0 = 0.f, yv1 = 0.f;
        if (rok && (unsigned)gc < 512u)       { xv0 = xp[o];     yv0 = yp[o]; }
        if (rok && (unsigned)(gc + 1) < 512u) { xv1 = xp[o + 1]; yv1 = yp[o + 1]; }
        sxy2[r * SXW + t] = make_uint2(
            h2u(__builtin_amdgcn_cvt_pkrtz(xv0, xv1)),
            h2u(__builtin_amdgcn_cvt_pkrtz(yv0, yv1)));
    }
    __syncthreads();

    // Tap vectors in f16, center-corrected so the f16 tap set sums to ~1.
    h2 ge[6], go[6];
    {
        float gf[11]; float ssum = 0.0f;
        #pragma unroll
        for (int k = 0; k < 11; ++k) {
            gf[k] = (float)(_Float16)gs[k];
            if (k != 5) ssum += gf[k];
        }
        gf[5] = 1.0f - ssum;
        _Float16 gh[12];
        #pragma unroll
        for (int k = 0; k < 11; ++k) gh[k] = (_Float16)gf[k];
        gh[11] = (_Float16)0.0f;
        #pragma unroll
        for (int t = 0; t < 6; ++t) {
            ge[t][0] = gh[2 * t]; ge[t][1] = gh[2 * t + 1];           // (g0,g1)..(g10,0)
            go[t][0] = (t == 0) ? (_Float16)0.0f : gh[2 * t - 1];     // (0,g0),(g1,g2)..
            go[t][1] = (t == 0) ? gh[0] : gh[2 * t];
        }
    }

    // conv4: 4 consecutive outputs (even,odd,even,odd phases) from 7 pairs.
    auto conv4 = [&](const h2* s, float* o4) {
        float e0 = 0.f, o1 = 0.f, e2 = 0.f, o3 = 0.f;
        #pragma unroll
        for (int t = 0; t < 6; ++t) {
            e0 = fdot2_(ge[t], s[t],     e0);
            o1 = fdot2_(go[t], s[t],     o1);
            e2 = fdot2_(ge[t], s[t + 1], e2);
            o3 = fdot2_(go[t], s[t + 1], o3);
        }
        o4[0] = e0; o4[1] = o1; o4[2] = e2; o4[3] = o3;
    };

    // Phase B: horizontal conv. Item = (row-pair rp, col-quad cq): computes
    // rows 2rp,2rp+1 x 4 cols x 5 quantities; writes row-pair-packed h.
    if (tid < 21 * 8) {
        const int rp = tid >> 3, cq = tid & 7;
        float hv[2][5][4];
        #pragma unroll
        for (int e = 0; e < 2; ++e) {
            const int r = 2 * rp + e;
            const uint4* P = (const uint4*)&sxy2[r * SXW + 2 * cq];
            const uint4 A0 = P[0], A1 = P[1], A2 = P[2], A3 = P[3];
            h2 xh[8], yh[8];
            xh[0] = u2h(A0.x); yh[0] = u2h(A0.y); xh[1] = u2h(A0.z); yh[1] = u2h(A0.w);
            xh[2] = u2h(A1.x); yh[2] = u2h(A1.y); xh[3] = u2h(A1.z); yh[3] = u2h(A1.w);
            xh[4] = u2h(A2.x); yh[4] = u2h(A2.y); xh[5] = u2h(A2.z); yh[5] = u2h(A2.w);
            xh[6] = u2h(A3.x); yh[6] = u2h(A3.y); xh[7] = u2h(A3.z); yh[7] = u2h(A3.w);
            h2 xx[7], yy[7], xy[7];
            #pragma unroll
            for (int t = 0; t < 7; ++t) {
                xx[t] = xh[t] * xh[t];    // v_pk_mul_f16
                yy[t] = yh[t] * yh[t];
                xy[t] = xh[t] * yh[t];
            }
            conv4(xh, hv[e][0]);
            conv4(yh, hv[e][1]);
            conv4(xx, hv[e][2]);
            conv4(yy, hv[e][3]);
            conv4(xy, hv[e][4]);
        }
        #pragma unroll
        for (int qq = 0; qq < 5; ++qq) {
            uint4 w;
            w.x = h2u(__builtin_amdgcn_cvt_pkrtz(hv[0][qq][0], hv[1][qq][0]));
            w.y = h2u(__builtin_amdgcn_cvt_pkrtz(hv[0][qq][1], hv[1][qq][1]));
            w.z = h2u(__builtin_amdgcn_cvt_pkrtz(hv[0][qq][2], hv[1][qq][2]));
            w.w = h2u(__builtin_amdgcn_cvt_pkrtz(hv[0][qq][3], hv[1][qq][3]));
            *(uint4*)&hp[(qq * 21 + rp) * HPW + 4 * cq] = w;
        }
    }
    __syncthreads();

    // Phase C: vertical conv + SSIM. Thread = (row r, col-quad cq) — exactly
    // 256 items. Row parity picks the tap vector; pairs span rows 2m..2m+11.
    const int r = tid >> 3, cq = tid & 7, m = r >> 1;
    h2 gsel[6];
    #pragma unroll
    for (int t = 0; t < 6; ++t) gsel[t] = (r & 1) ? go[t] : ge[t];

    float acc[5][4];
    #pragma unroll
    for (int qq = 0; qq < 5; ++qq) {
        float a0 = 0.f, a1 = 0.f, a2 = 0.f, a3 = 0.f;
        #pragma unroll
        for (int t = 0; t < 6; ++t) {
            const uint4 V = *(const uint4*)&hp[(qq * 21 + m + t) * HPW + 4 * cq];
            a0 = fdot2_(gsel[t], u2h(V.x), a0);
            a1 = fdot2_(gsel[t], u2h(V.y), a1);
            a2 = fdot2_(gsel[t], u2h(V.z), a2);
            a3 = fdot2_(gsel[t], u2h(V.w), a3);
        }
        acc[qq][0] = a0; acc[qq][1] = a1; acc[qq][2] = a2; acc[qq][3] = a3;
    }

    float lsum = 0.0f;
    const float C1 = 1e-4f, C2 = 9e-4f;
    #pragma unroll
    for (int j = 0; j < 4; ++j) {
        const float mx = acc[0][j], my = acc[1][j];
        const float exx = acc[2][j], eyy = acc[3][j], exy = acc[4][j];
        const float mx2 = mx * mx, my2 = my * my, mxy = mx * my;
        const float vx = exx - mx2, vy = eyy - my2, vxy = exy - mxy;
        const float num = (2.0f * mxy + C1) * (2.0f * vxy + C2);
        const float den = (mx2 + my2 + C1) * (vx + vy + C2) + 1e-12f;
        lsum = fmaf(num, __builtin_amdgcn_rcpf(den), lsum);
    }

    // Wave reduce -> cross-wave via LDS -> one plain store per block.
    #pragma unroll
    for (int off = 32; off > 0; off >>= 1)
        lsum += __shfl_down(lsum, off, 64);
    if ((tid & 63) == 0) wred[tid >> 6] = lsum;
    __syncthreads();
    if (tid == 0) {
        const int bid = (blockIdx.z * gridDim.y + blockIdx.y) * gridDim.x
                        + blockIdx.x;
        part[bid] = wred[0] + wred[1] + wred[2] + wred[3];
    }
}

__global__ __launch_bounds__(256) void ssim_reduce(
    const float* __restrict__ part, float* __restrict__ out,
    int n, float invN)
{
    __shared__ float wred[4];
    float s = 0.0f;
    for (int i = threadIdx.x; i < n; i += 256) s += part[i];
    #pragma unroll
    for (int off = 32; off > 0; off >>= 1)
        s += __shfl_down(s, off, 64);
    if ((threadIdx.x & 63) == 0) wred[threadIdx.x >> 6] = s;
    __syncthreads();
    if (threadIdx.x == 0)
        out[0] = 1.0f - (wred[0] + wred[1] + wred[2] + wred[3]) * invN;
}

extern "C" void kernel_launch(void* const* d_in, const int* in_sizes, int n_in,
                              void* d_out, int out_size, void* d_ws, size_t ws_size,
                              hipStream_t stream) {
    const float* x   = (const float*)d_in[0];
    const float* y   = (const float*)d_in[1];
    const float* w2d = (const float*)d_in[2];  // (3,1,11,11); channels identical
    float* out  = (float*)d_out;
    float* part = (float*)d_ws;                // 12288 floats = 48 KB

    const int H = 512, W = 512;
    const int total = in_sizes[0];              // 16*3*512*512
    const int Z = total / (H * W);              // 48

    dim3 grid(W / 32, H / 32, Z);               // 16 x 16 x 48 = 12288 blocks
    const int nblocks = (W / 32) * (H / 32) * Z;
    ssim_main<<<grid, 256, 0, stream>>>(x, y, w2d, part);

    const float invN = 1.0f / (float)total;
    ssim_reduce<<<1, 256, 0, stream>>>(part, out, nblocks, invN);
}